// Round 10
// baseline (144.523 us; speedup 1.0000x reference)
//
#include <hip/hip_runtime.h>

#define GAT_H 12
#define GAT_N 4096
#define GAT_F 64
#define BR 32                       // rows per block
#define BH 3                        // heads per block
#define LOG2E 1.4426950408889634f

// ---------------------------------------------------------------------------
// Algebra: with q = x_i*s_h + x_j*d_h,
//   exp(lrelu(q)) = B1(i,h) * max(E2^4, rho(i,h)) * E2
//   where E2  = exp2(0.2*log2e*d_h*x_j)   [192 KB table]
//         rho = exp2(-0.8*log2e*x_i*s_h)  [SGPR-pinned]
// B1 cancels in softmax. Inner per (i,j,h): shared sq/sq + max+mul+2fma.
//
// R8 lesson: __syncthreads() == s_waitcnt vmcnt(0) + s_barrier -> ANY
// in-loop barrier drains the prefetch pipe every iteration (~60% of wall).
// R9: barrier-FREE K-loop. Block = (3-head group) x (32 rows); the 48 KB
// table slice is staged ONCE (read-only afterwards), so the loop has no
// LDS writes and no barriers. adj/x register-prefetched depth 2 (counted
// per-register vmcnt, genuinely in flight). 4 rows x 3 heads = 24
// accumulators/wave (R5-proven allocator-safe at 512 threads); e-outer
// compute keeps transients at 8 regs. ds_read_b128: one base + imm offsets.
// ---------------------------------------------------------------------------

__device__ float g_tab2[GAT_H * GAT_N];   // 192 KB: E2 table
__device__ float g_sd[2 * GAT_H + 1];     // s[12], d[12], mean(x)

__global__ __launch_bounds__(256) void gat_prep(const float* __restrict__ W,
                                                const float* __restrict__ a,
                                                const float* __restrict__ x) {
    const int b    = blockIdx.x;
    const int tid  = threadIdx.x;
    const int lane = tid & 63;
    const int wave = tid >> 6;

    if (b < GAT_H) {                       // s_h, d_h (wave 0 only)
        if (wave == 0) {
            const float wf = W[b * GAT_F + lane];
            float ps = wf * a[b * 2 * GAT_F + lane];
            float pd = wf * a[b * 2 * GAT_F + GAT_F + lane];
            #pragma unroll
            for (int off = 32; off > 0; off >>= 1) {
                ps += __shfl_xor(ps, off, 64);
                pd += __shfl_xor(pd, off, 64);
            }
            if (lane == 0) { g_sd[b] = ps; g_sd[GAT_H + b] = pd; }
        }
        return;
    }
    if (b == GAT_H) {                      // mean(x) fallback (wave 0 only)
        if (wave == 0) {
            float s = 0.0f;
            #pragma unroll
            for (int j = 0; j < GAT_N / 64; ++j) s += x[j * 64 + lane];
            #pragma unroll
            for (int off = 32; off > 0; off >>= 1) s += __shfl_xor(s, off, 64);
            if (lane == 0) g_sd[2 * GAT_H] = s * (1.0f / GAT_N);
        }
        return;
    }

    // Table blocks: bt in [0,48): h = bt>>2, 1024-wide j-chunk = bt&3.
    const int bt    = b - (GAT_H + 1);
    const int h     = bt >> 2;
    const int chunk = bt & 3;
    const float wf  = W[h * GAT_F + lane];
    float pd = wf * a[h * 2 * GAT_F + GAT_F + lane];
    #pragma unroll
    for (int off = 32; off > 0; off >>= 1) pd += __shfl_xor(pd, off, 64);
    const float dl5 = 0.2f * pd * LOG2E;
    #pragma unroll
    for (int k = 0; k < 4; ++k) {
        const int j = chunk * 1024 + k * 256 + tid;
        g_tab2[h * GAT_N + j] = __builtin_amdgcn_exp2f(dl5 * x[j]);
    }
}

// Main: grid = (4096/BR) * 4 = 512 blocks. 8 waves, each owns 4 rows x 3 heads.
__global__ __launch_bounds__(512) void gat_main(const float* __restrict__ x,
                                                const int* __restrict__ adj,
                                                const float* __restrict__ W,
                                                float* __restrict__ out) {
    __shared__ float tabs[BH][GAT_N];     // 48 KB, read-only after prologue
    __shared__ float cbuf[BR][BH];

    const int tid  = threadIdx.x;
    const int lane = tid & 63;
    const int wid  = tid >> 6;            // 0..7
    const int hb   = (blockIdx.x & 3) * BH;      // head base (0,3,6,9)
    const int row0 = (blockIdx.x >> 2) * BR;
    const int rA   = row0 + wid * 4;             // this wave's 4 rows

    // Stage the 3-head table slice once (6 float4 per thread).
    const float4* __restrict__ tg4 = (const float4*)(g_tab2 + hb * GAT_N);
    float4* ls4 = (float4*)tabs;
    #pragma unroll
    for (int k = 0; k < (BH * GAT_N / 4) / 512; ++k)
        ls4[k * 512 + tid] = tg4[k * 512 + tid];

    // rho (wave-uniform) -> SGPR-pinned
    float rho[4][BH];
    #pragma unroll
    for (int r = 0; r < 4; ++r) {
        const float xr = x[rA + r];
        #pragma unroll
        for (int hh = 0; hh < BH; ++hh)
            rho[r][hh] = __uint_as_float(__builtin_amdgcn_readfirstlane(
                __float_as_uint(__builtin_amdgcn_exp2f(
                    -0.8f * LOG2E * xr * g_sd[hb + hh]))));
    }

    float den[4][BH], num[4][BH];
    #pragma unroll
    for (int r = 0; r < 4; ++r)
        #pragma unroll
        for (int hh = 0; hh < BH; ++hh) { den[r][hh] = 0.0f; num[r][hh] = 0.0f; }

    // 4 j per lane: j = it*256 + 4*lane + e
    const int4*   __restrict__ a4 = (const int4*)(adj + (size_t)rA * GAT_N);
    const float4* __restrict__ x4 = (const float4*)x;

    // adj/x pipe, depth 2 (no barriers anywhere in the loop -> stays in flight)
    int4   aP[2][4];
    float4 xP[2];
    #pragma unroll
    for (int r = 0; r < 4; ++r) {
        aP[0][r] = a4[r * (GAT_N / 4) + lane];
        aP[1][r] = a4[r * (GAT_N / 4) + 64 + lane];
    }
    xP[0] = x4[lane];
    xP[1] = x4[64 + lane];

    __syncthreads();                       // table visible; the ONLY loop barrier

    #pragma unroll 2
    for (int it = 0; it < 16; ++it) {
        const int buf = it & 1;            // literal under unroll-2

        // consume pipe slot (rename, no copies survive)
        int4   aC[4];
        float4 xC = xP[buf];
        #pragma unroll
        for (int r = 0; r < 4; ++r) aC[r] = aP[buf][r];

        // refill slot with it+2 (consumed two iterations from now)
        const int n2i = ((it < 14) ? it + 2 : 15) * 64 + lane;
        #pragma unroll
        for (int r = 0; r < 4; ++r) aP[buf][r] = a4[r * (GAT_N / 4) + n2i];
        xP[buf] = x4[n2i];

        // table reads: one base VGPR + immediate offsets, conflict-free
        float4 e2v[BH];
        #pragma unroll
        for (int hh = 0; hh < BH; ++hh)
            e2v[hh] = *(const float4*)&tabs[hh][it * 256 + 4 * lane];

        // e-outer compute keeps mask transients to 8 regs
        const float* xp = (const float*)&xC;
        #pragma unroll
        for (int e = 0; e < 4; ++e) {
            float am[4], axj[4];
            #pragma unroll
            for (int r = 0; r < 4; ++r) {
                const int ai = ((const int*)&aC[r])[e];
                am[r]  = (float)ai;                // adj in {0,1}
                axj[r] = am[r] * xp[e];
            }
            #pragma unroll
            for (int hh = 0; hh < BH; ++hh) {
                const float ev = ((const float*)&e2v[hh])[e];
                const float w  = ev * ev;
                const float w4 = w * w;                          // E2^4
                #pragma unroll
                for (int r = 0; r < 4; ++r) {
                    const float p = fmaxf(w4, rho[r][hh]) * ev;  // max(E1,rho*E2)
                    den[r][hh] = fmaf(p, am[r],  den[r][hh]);
                    num[r][hh] = fmaf(p, axj[r], num[r][hh]);
                }
            }
        }
    }

    // Each (row, head) owned by exactly one wave: reduce and write directly.
    #pragma unroll
    for (int r = 0; r < 4; ++r) {
        #pragma unroll
        for (int hh = 0; hh < BH; ++hh) {
            float d = den[r][hh], n = num[r][hh];
            #pragma unroll
            for (int off = 32; off > 0; off >>= 1) {
                d += __shfl_xor(d, off, 64);
                n += __shfl_xor(n, off, 64);
            }
            if (lane == 0)
                cbuf[wid * 4 + r][hh] = d > 0.0f ? n / d : g_sd[2 * GAT_H];
        }
    }
    __syncthreads();

    // Epilogue: out[row][(hb+hh)*64+f] = c[row][hh] * W[(hb+hh)*64+f].
    #pragma unroll
    for (int q = 0; q < BR * BH / 8; ++q) {
        const int qq  = q * 8 + wid;
        const int row = qq / BH;
        const int hh  = qq - row * BH;
        out[(size_t)(row0 + row) * (GAT_H * GAT_F) + (hb + hh) * GAT_F + lane] =
            cbuf[row][hh] * W[(hb + hh) * GAT_F + lane];
    }
}

extern "C" void kernel_launch(void* const* d_in, const int* in_sizes, int n_in,
                              void* d_out, int out_size, void* d_ws, size_t ws_size,
                              hipStream_t stream) {
    const float* x   = (const float*)d_in[0];
    const int*   adj = (const int*)d_in[1];
    const float* W   = (const float*)d_in[2];
    const float* a   = (const float*)d_in[3];
    float* out = (float*)d_out;
    (void)d_ws; (void)ws_size;   // all scratch is static __device__ memory

    gat_prep<<<GAT_H + 1 + 48, 256, 0, stream>>>(W, a, x);
    gat_main<<<(GAT_N / BR) * 4, 512, 0, stream>>>(x, adj, W, out);
}